// Round 4
// baseline (1345.816 us; speedup 1.0000x reference)
//
#include <hip/hip_runtime.h>
#include <hip/hip_bf16.h>
#include <cstdint>

#define T_TOKENS 2048
#define HIDDEN 2048
#define INTER 1408
#define NEXP 16
#define TOPK 4
#define SINTER 2816
#define CAP 768
#define BK 32

typedef __attribute__((ext_vector_type(8))) short short8;
typedef __attribute__((ext_vector_type(8))) unsigned short ushort8;
typedef __attribute__((ext_vector_type(4))) unsigned short ushort4v;
typedef __attribute__((ext_vector_type(4))) float f32x4;

__device__ __forceinline__ float4 ld4f(const float* p) {
  return *reinterpret_cast<const float4*>(p);
}

// bf16 split: v ~= hi + lo, each bf16 (RNE). |v - hi - lo| <~ 2^-17 |v|
__device__ __forceinline__ unsigned short f2bf(float v) {
  unsigned int u = __float_as_uint(v);
  unsigned int r = (u + 0x7FFFu + ((u >> 16) & 1u)) >> 16;
  return (unsigned short)r;
}
__device__ __forceinline__ float bf2f(unsigned short b) {
  return __uint_as_float(((unsigned int)b) << 16);
}
__device__ __forceinline__ void bsplit(float v, unsigned short& h, unsigned short& l) {
  h = f2bf(v);
  l = f2bf(v - bf2f(h));
}

__device__ __forceinline__ void gld16(const void* g, void* l) {
  __builtin_amdgcn_global_load_lds(
      (const __attribute__((address_space(1))) void*)g,
      (__attribute__((address_space(3))) void*)l, 16, 0, 0);
}

// ---------------- router: logits -> softmax -> top4 ----------------
__global__ __launch_bounds__(64) void router_kernel(
    const float* __restrict__ x, const float* __restrict__ wg,
    int* __restrict__ topi, float* __restrict__ topw)
{
  const int t = blockIdx.x;
  const int lane = threadIdx.x;
  float acc[NEXP];
#pragma unroll
  for (int e = 0; e < NEXP; ++e) acc[e] = 0.f;
  const float* xr = x + (size_t)t * HIDDEN;
  for (int i = lane; i < HIDDEN; i += 64) {
    float xv = xr[i];
#pragma unroll
    for (int e = 0; e < NEXP; ++e) acc[e] += xv * wg[e * HIDDEN + i];
  }
#pragma unroll
  for (int e = 0; e < NEXP; ++e) {
#pragma unroll
    for (int off = 32; off > 0; off >>= 1)
      acc[e] += __shfl_xor(acc[e], off);
  }
  float m = acc[0];
#pragma unroll
  for (int e = 1; e < NEXP; ++e) m = fmaxf(m, acc[e]);
  float p[NEXP];
  float s = 0.f;
#pragma unroll
  for (int e = 0; e < NEXP; ++e) { p[e] = expf(acc[e] - m); s += p[e]; }
  const float inv = 1.f / s;
#pragma unroll
  for (int e = 0; e < NEXP; ++e) p[e] *= inv;
  if (lane == 0) {
#pragma unroll
    for (int k = 0; k < TOPK; ++k) {
      float best = -1.f; int bi = 0;
#pragma unroll
      for (int e = 0; e < NEXP; ++e)
        if (p[e] > best) { best = p[e]; bi = e; }   // strict >: lowest idx on tie
      topi[t * TOPK + k] = bi;
      topw[t * TOPK + k] = best;  // ROUTED_SCALE = 1.0
      p[bi] = -1.f;
    }
  }
}

// ------------- stable partition: slot -> (expert,pos), exact cumsum order -------------
__global__ __launch_bounds__(1024) void partition_kernel(
    const int* __restrict__ topi, float* __restrict__ topw,
    int* __restrict__ rowtok, int* __restrict__ count)
{
  __shared__ int se[T_TOKENS * TOPK];
  for (int i = threadIdx.x; i < T_TOKENS * TOPK; i += 1024) se[i] = topi[i];
  __syncthreads();

  const int wave = threadIdx.x >> 6;   // 16 waves = 16 experts
  const int lane = threadIdx.x & 63;
  const uint64_t below = (lane == 0) ? 0ull : ((~0ull) >> (64 - lane));
  int base = 0;
  for (int c = 0; c < T_TOKENS * TOPK; c += 64) {
    int ev = se[c + lane];
    uint64_t mask = __ballot(ev == wave);
    if (ev == wave) {
      int my = base + __popcll(mask & below);
      if (my < CAP) rowtok[wave * CAP + my] = c + lane;   // slot id
      else          topw[c + lane] = 0.f;                 // capacity drop
    }
    base += __popcll(mask);
  }
  if (lane == 0) count[wave] = base < CAP ? base : CAP;
}

// ------------- elementwise split: x -> hi/lo planes -------------
__global__ __launch_bounds__(256) void split_x_kernel(
    const float* __restrict__ x, unsigned short* __restrict__ hi,
    unsigned short* __restrict__ lo)
{
  const long i = ((long)blockIdx.x * 256 + threadIdx.x) * 8;
  float4 a = ld4f(x + i), b = ld4f(x + i + 4);
  float v[8] = {a.x, a.y, a.z, a.w, b.x, b.y, b.z, b.w};
  unsigned short h[8], l[8];
#pragma unroll
  for (int j = 0; j < 8; ++j) bsplit(v[j], h[j], l[j]);
  *(ushort8*)(hi + i) = *(ushort8*)&h[0];
  *(ushort8*)(lo + i) = *(ushort8*)&l[0];
}

// ------------- transpose + split: W[K][N] -> T{hi,lo}[N][K] (per expert z) -------------
__global__ __launch_bounds__(256) void tsplit_w_kernel(
    const float* __restrict__ W, unsigned short* __restrict__ Thi,
    unsigned short* __restrict__ Tlo, int K, int N)
{
  const long z = blockIdx.z;
  W   += z * (long)K * N;
  Thi += z * (long)K * N;
  Tlo += z * (long)K * N;
  const int k0 = blockIdx.x * 64, n0 = blockIdx.y * 64;
  __shared__ float tile[64][65];
  const int tr = threadIdx.x >> 4;          // 0..15
  const int tc4 = (threadIdx.x & 15) * 4;   // 0..60
#pragma unroll
  for (int p = 0; p < 4; ++p) {
    int r = p * 16 + tr;
    float4 v = ld4f(W + (long)(k0 + r) * N + n0 + tc4);
    tile[r][tc4] = v.x; tile[r][tc4 + 1] = v.y;
    tile[r][tc4 + 2] = v.z; tile[r][tc4 + 3] = v.w;
  }
  __syncthreads();
  const int wn = threadIdx.x >> 3;          // 0..31
  const int wk = (threadIdx.x & 7) * 8;     // 0..56
#pragma unroll
  for (int p = 0; p < 2; ++p) {
    int n = p * 32 + wn;
    unsigned short h8[8], l8[8];
#pragma unroll
    for (int j = 0; j < 8; ++j) bsplit(tile[wk + j][n], h8[j], l8[j]);
    long off = (long)(n0 + n) * K + k0 + wk;
    *(ushort8*)(Thi + off) = *(ushort8*)&h8[0];
    *(ushort8*)(Tlo + off) = *(ushort8*)&l8[0];
  }
}

// ------------- dual-plane bf16 MFMA GEMM (3 MFMA: hh+hl+lh), gload_lds staged -------------
// 128x128 tile, BK=32, 4 waves (2x2), wave tile 64x64.
// Counted-vmcnt pipeline (raw barriers; stage(t+1) waits a full iteration).
// 1D grid, bijective XCD chunking, m-tile-fastest decode (B-panel sharers colocate).
template<int EPI>   // 0: C fp32; 1: read G fp32, write silu(G)*acc split into Chi/Clo
__global__ __launch_bounds__(256, 2)
void gemm_bf3(const unsigned short* __restrict__ Ahi_g, const unsigned short* __restrict__ Alo_g,
              int lda,
              const unsigned short* __restrict__ Bhi_g, const unsigned short* __restrict__ Blo_g,
              long bstride,
              float* __restrict__ C, unsigned short* __restrict__ Chi, unsigned short* __restrict__ Clo,
              int ldc, const float* __restrict__ G,
              const int* __restrict__ arows_g, int ashift, long aexp,
              const int* __restrict__ crows_g, long cexp,
              const int* __restrict__ cnt, int Mfix, int K,
              int MT, int NTn)
{
  // bijective XCD chunk (nwg % 8 == 0 for all our launches)
  const int nwg = gridDim.x;
  const int lin = (blockIdx.x & 7) * (nwg >> 3) + (blockIdx.x >> 3);
  const int mt = lin % MT;
  const int rest = lin / MT;
  const int nt = rest % NTn;
  const int e = rest / NTn;

  const int M = cnt ? cnt[e] : Mfix;
  if (mt * 128 >= M) return;
  const int n0 = nt * 128;
  const int tid = threadIdx.x;
  const int lane = tid & 63;
  const int wave = tid >> 6;
  const int wr = (wave >> 1) * 64;
  const int wc = (wave & 1) * 64;

  const int* arows = arows_g ? arows_g + e * CAP : nullptr;
  const int* crows = crows_g ? crows_g + e * CAP : nullptr;
  const unsigned short* Bhi = Bhi_g + (long)e * bstride;
  const unsigned short* Blo = Blo_g + (long)e * bstride;

  // [buf][plane][128 rows * 32 k] ushorts; rows are 64 B, linear (gload_lds friendly)
  __shared__ __align__(16) unsigned short sA[2][2][128 * BK];
  __shared__ __align__(16) unsigned short sB[2][2][128 * BK];

  // staging: wave w covers 16-row groups i = 2w, 2w+1 of each plane-array.
  const int lr = lane >> 2;
  const int ch = lane & 3;
  long offA[2], offB[2];
#pragma unroll
  for (int j = 0; j < 2; ++j) {
    const int i = wave * 2 + j;
    const int rloc = i * 16 + lr;             // 0..127
    int r = mt * 128 + rloc;
    if (r > M - 1) r = M - 1;
    const long arow = arows ? (long)(arows[r] >> ashift) : (aexp * e + r);
    offA[j] = arow * lda + ch * 8;            // element offset
    offB[j] = (long)(n0 + rloc) * K + ch * 8;
  }

  f32x4 acc[4][4];
#pragma unroll
  for (int i = 0; i < 4; ++i)
#pragma unroll
    for (int j = 0; j < 4; ++j) acc[i][j] = (f32x4)0.f;

  const int fr = lane & 15;
  const int fc = lane >> 4;
  const int NT = K / BK;

  auto stage = [&](int buf, int kt) {
#pragma unroll
    for (int j = 0; j < 2; ++j) {
      const int i = wave * 2 + j;
      const long ka = offA[j] + kt;
      const long kb = offB[j] + kt;
      gld16(Ahi_g + ka, &sA[buf][0][i * 512]);
      gld16(Alo_g + ka, &sA[buf][1][i * 512]);
      gld16(Bhi + kb,   &sB[buf][0][i * 512]);
      gld16(Blo + kb,   &sB[buf][1][i * 512]);
    }
  };

  stage(0, 0);   // 8 loads in flight

  for (int t = 0; t < NT; ++t) {
    const int cur = t & 1;
    // #1: all waves finished their ds_reads of buf[cur^1] (prev iter)
    asm volatile("s_waitcnt lgkmcnt(0)" ::: "memory");
    __builtin_amdgcn_s_barrier();
    if (t + 1 < NT) {
      stage(cur ^ 1, (t + 1) * BK);                       // 8 more loads
      asm volatile("s_waitcnt vmcnt(8)" ::: "memory");    // stage(t) landed
    } else {
      asm volatile("s_waitcnt vmcnt(0)" ::: "memory");
    }
    // #2: every wave's stage(t) landed -> buf[cur] readable
    __builtin_amdgcn_s_barrier();
    __builtin_amdgcn_sched_barrier(0);

    short8 fah[4], fal[4], fbh[4], fbl[4];
#pragma unroll
    for (int mi = 0; mi < 4; ++mi) {
      const int idx = (wr + mi * 16 + fr) * BK + fc * 8;
      fah[mi] = *(const short8*)&sA[cur][0][idx];
      fal[mi] = *(const short8*)&sA[cur][1][idx];
    }
#pragma unroll
    for (int ni = 0; ni < 4; ++ni) {
      const int idx = (wc + ni * 16 + fr) * BK + fc * 8;
      fbh[ni] = *(const short8*)&sB[cur][0][idx];
      fbl[ni] = *(const short8*)&sB[cur][1][idx];
    }
#pragma unroll
    for (int mi = 0; mi < 4; ++mi)
#pragma unroll
      for (int ni = 0; ni < 4; ++ni) {
        acc[mi][ni] = __builtin_amdgcn_mfma_f32_16x16x32_bf16(fah[mi], fbh[ni], acc[mi][ni], 0, 0, 0);
        acc[mi][ni] = __builtin_amdgcn_mfma_f32_16x16x32_bf16(fah[mi], fbl[ni], acc[mi][ni], 0, 0, 0);
        acc[mi][ni] = __builtin_amdgcn_mfma_f32_16x16x32_bf16(fal[mi], fbh[ni], acc[mi][ni], 0, 0, 0);
      }
  }

  // epilogue: C/D layout col=lane&15, row=(lane>>4)*4+rr
#pragma unroll
  for (int mi = 0; mi < 4; ++mi)
#pragma unroll
    for (int rr = 0; rr < 4; ++rr) {
      const int r = mt * 128 + wr + mi * 16 + fc * 4 + rr;
      if (r >= M) continue;
      const long crow = crows ? (long)crows[r] : (cexp * e + r);
#pragma unroll
      for (int ni = 0; ni < 4; ++ni) {
        const int col = n0 + wc + ni * 16 + fr;
        const long off = crow * ldc + col;
        const float v = acc[mi][ni][rr];
        if constexpr (EPI == 1) {
          const float g = G[off];
          const float h = v * (g / (1.f + __expf(-g)));   // silu(g)*u
          unsigned short hh, hl;
          bsplit(h, hh, hl);
          Chi[off] = hh; Clo[off] = hl;
        } else {
          C[off] = v;
        }
      }
    }
}

// ------------- combine: out[t] += sum_k w_k * o_slot[t*4+k] -------------
__global__ __launch_bounds__(256) void combine_kernel(
    const float* __restrict__ o_slot, const float* __restrict__ topw,
    float* __restrict__ out)
{
  const int t = blockIdx.x;
  float w[TOPK];
#pragma unroll
  for (int k = 0; k < TOPK; ++k) w[k] = topw[t * TOPK + k];
  float* orow = out + (size_t)t * HIDDEN;
  for (int c = threadIdx.x * 4; c < HIDDEN; c += 256 * 4) {
    float4 acc = *reinterpret_cast<float4*>(orow + c);
#pragma unroll
    for (int k = 0; k < TOPK; ++k) {
      if (w[k] != 0.f) {
        float4 v = ld4f(o_slot + ((size_t)(t * TOPK + k)) * HIDDEN + c);
        acc.x += w[k] * v.x; acc.y += w[k] * v.y;
        acc.z += w[k] * v.z; acc.w += w[k] * v.w;
      }
    }
    *reinterpret_cast<float4*>(orow + c) = acc;
  }
}

extern "C" void kernel_launch(void* const* d_in, const int* in_sizes, int n_in,
                              void* d_out, int out_size, void* d_ws, size_t ws_size,
                              hipStream_t stream)
{
  const float* x   = (const float*)d_in[0];
  const float* wg  = (const float*)d_in[1];
  const float* w1  = (const float*)d_in[2];
  const float* w3  = (const float*)d_in[3];
  const float* w2  = (const float*)d_in[4];
  const float* ws1 = (const float*)d_in[5];
  const float* ws3 = (const float*)d_in[6];
  const float* ws2 = (const float*)d_in[7];
  float* out = (float*)d_out;

  char* w = (char*)d_ws;
  int*   topi   = (int*)w;   w += (size_t)T_TOKENS * TOPK * 4;
  float* topw   = (float*)w; w += (size_t)T_TOKENS * TOPK * 4;
  int*   rowtok = (int*)w;   w += (size_t)NEXP * CAP * 4;
  int*   count  = (int*)w;   w += 256;
  uintptr_t a = (uintptr_t)w; a = (a + 255) & ~(uintptr_t)255; w = (char*)a;

  const size_t XSZ  = (size_t)T_TOKENS * HIDDEN;          // 4.19M
  const size_t WSSZ = (size_t)HIDDEN * SINTER;            // 5.77M
  const size_t WRSZ = (size_t)NEXP * HIDDEN * INTER;      // 46.1M
  const size_t HSSZ = (size_t)T_TOKENS * SINTER;          // 5.77M
  const size_t HRSZ = (size_t)NEXP * CAP * INTER;         // 17.3M

  unsigned short* xhi  = (unsigned short*)w; w += XSZ * 2;
  unsigned short* xlo  = (unsigned short*)w; w += XSZ * 2;
  unsigned short* wShi = (unsigned short*)w; w += WSSZ * 2;   // rotated ws1T/ws3T/ws2T
  unsigned short* wSlo = (unsigned short*)w; w += WSSZ * 2;
  unsigned short* wRhi = (unsigned short*)w; w += WRSZ * 2;   // rotated w1T/w3T/w2T
  unsigned short* wRlo = (unsigned short*)w; w += WRSZ * 2;
  unsigned short* hShi = (unsigned short*)w; w += HSSZ * 2;
  unsigned short* hSlo = (unsigned short*)w; w += HSSZ * 2;
  unsigned short* hRhi = (unsigned short*)w; w += HRSZ * 2;
  unsigned short* hRlo = (unsigned short*)w; w += HRSZ * 2;
  float* gbuf = (float*)w;   w += (size_t)NEXP * CAP * INTER * 4;  // g_s / g_r / o_slot (69.2 MB)
  float* o_slot = gbuf;      // o_slot [8192][2048] fp32 = 67.1 MB fits in g region

  router_kernel<<<T_TOKENS, 64, 0, stream>>>(x, wg, topi, topw);
  partition_kernel<<<1, 1024, 0, stream>>>(topi, topw, rowtok, count);
  split_x_kernel<<<(int)(XSZ / (256 * 8)), 256, 0, stream>>>(x, xhi, xlo);

  // ---- shared up/gate ----
  tsplit_w_kernel<<<dim3(HIDDEN / 64, SINTER / 64, 1), 256, 0, stream>>>(ws1, wShi, wSlo, HIDDEN, SINTER);
  gemm_bf3<0><<<(T_TOKENS / 128) * (SINTER / 128), 256, 0, stream>>>(
      xhi, xlo, HIDDEN, wShi, wSlo, 0L, gbuf, nullptr, nullptr, SINTER, nullptr,
      nullptr, 0, 0L, nullptr, 0L, nullptr, T_TOKENS, HIDDEN,
      T_TOKENS / 128, SINTER / 128);
  tsplit_w_kernel<<<dim3(HIDDEN / 64, SINTER / 64, 1), 256, 0, stream>>>(ws3, wShi, wSlo, HIDDEN, SINTER);
  gemm_bf3<1><<<(T_TOKENS / 128) * (SINTER / 128), 256, 0, stream>>>(
      xhi, xlo, HIDDEN, wShi, wSlo, 0L, nullptr, hShi, hSlo, SINTER, gbuf,
      nullptr, 0, 0L, nullptr, 0L, nullptr, T_TOKENS, HIDDEN,
      T_TOKENS / 128, SINTER / 128);

  // ---- routed up/gate (A rows gathered by token; C rows compact e*CAP+r) ----
  tsplit_w_kernel<<<dim3(HIDDEN / 64, INTER / 64, NEXP), 256, 0, stream>>>(w1, wRhi, wRlo, HIDDEN, INTER);
  gemm_bf3<0><<<(CAP / 128) * (INTER / 128) * NEXP, 256, 0, stream>>>(
      xhi, xlo, HIDDEN, wRhi, wRlo, (long)INTER * HIDDEN, gbuf, nullptr, nullptr, INTER, nullptr,
      rowtok, 2, 0L, nullptr, (long)CAP, count, 0, HIDDEN,
      CAP / 128, INTER / 128);
  tsplit_w_kernel<<<dim3(HIDDEN / 64, INTER / 64, NEXP), 256, 0, stream>>>(w3, wRhi, wRlo, HIDDEN, INTER);
  gemm_bf3<1><<<(CAP / 128) * (INTER / 128) * NEXP, 256, 0, stream>>>(
      xhi, xlo, HIDDEN, wRhi, wRlo, (long)INTER * HIDDEN, nullptr, hRhi, hRlo, INTER, gbuf,
      rowtok, 2, 0L, nullptr, (long)CAP, count, 0, HIDDEN,
      CAP / 128, INTER / 128);

  // ---- shared down: out = h_s @ ws2 ----
  tsplit_w_kernel<<<dim3(SINTER / 64, HIDDEN / 64, 1), 256, 0, stream>>>(ws2, wShi, wSlo, SINTER, HIDDEN);
  gemm_bf3<0><<<(T_TOKENS / 128) * (HIDDEN / 128), 256, 0, stream>>>(
      hShi, hSlo, SINTER, wShi, wSlo, 0L, out, nullptr, nullptr, HIDDEN, nullptr,
      nullptr, 0, 0L, nullptr, 0L, nullptr, T_TOKENS, SINTER,
      T_TOKENS / 128, HIDDEN / 128);

  // ---- routed down: o_slot = h_r @ w2 (A compact, C scattered to slot ids) ----
  tsplit_w_kernel<<<dim3(INTER / 64, HIDDEN / 64, NEXP), 256, 0, stream>>>(w2, wRhi, wRlo, INTER, HIDDEN);
  gemm_bf3<0><<<(CAP / 128) * (HIDDEN / 128) * NEXP, 256, 0, stream>>>(
      hRhi, hRlo, INTER, wRhi, wRlo, (long)HIDDEN * INTER, o_slot, nullptr, nullptr, HIDDEN, nullptr,
      nullptr, 0, (long)CAP, rowtok, 0L, count, 0, INTER,
      CAP / 128, HIDDEN / 128);

  combine_kernel<<<T_TOKENS, 256, 0, stream>>>(o_slot, topw, out);
}